// Round 1
// baseline (256.980 us; speedup 1.0000x reference)
//
#include <hip/hip_runtime.h>
#include <stdint.h>

// AugmentationPipeline: bit-exact JAX threefry (partitionable path) on device.
// B=32768 rows, L=512. One 256-thread block per row.
// Out layout (int32): mask_seq[B*L] | mask_len[B] | crop_seq[B*L] | crop_len[B]
//                     | reord_seq[B*L] | reord_len[B]

#define NB 32768
#define NL 512
#define NBL (NB * NL)

struct AugKeys {
  uint32_t km0, km1;   // mask key
  uint32_t kc0, kc1;   // crop key
  uint32_t r10, r11;   // reorder k1 (wsize)
  uint32_t r20, r21;   // reorder k2 (start)
  uint32_t r30, r31;   // reorder k3 (apply)
  uint32_t r40, r41;   // reorder k4 (window keys, shape (B,5))
};

__host__ __device__ __forceinline__ uint32_t rotl32(uint32_t x, uint32_t r) {
  return (x << r) | (x >> (32u - r));
}

// Threefry-2x32, 20 rounds (JAX's threefry2x32_p).
__host__ __device__ inline void tf2x32(uint32_t k0, uint32_t k1,
                                       uint32_t x0, uint32_t x1,
                                       uint32_t& o0, uint32_t& o1) {
  const uint32_t ks2 = k0 ^ k1 ^ 0x1BD11BDAu;
#define TFR(r) { x0 += x1; x1 = rotl32(x1, r); x1 ^= x0; }
  x0 += k0; x1 += k1;
  TFR(13u) TFR(15u) TFR(26u) TFR(6u)
  x0 += k1; x1 += ks2 + 1u;
  TFR(17u) TFR(29u) TFR(16u) TFR(24u)
  x0 += ks2; x1 += k0 + 2u;
  TFR(13u) TFR(15u) TFR(26u) TFR(6u)
  x0 += k0; x1 += k1 + 3u;
  TFR(17u) TFR(29u) TFR(16u) TFR(24u)
  x0 += k1; x1 += ks2 + 4u;
  TFR(13u) TFR(15u) TFR(26u) TFR(6u)
  x0 += ks2; x1 += k0 + 5u;
#undef TFR
  o0 = x0; o1 = x1;
}

// JAX uniform(0,1) from 32 random bits.
__device__ __forceinline__ float u01f(uint32_t bits) {
  return __uint_as_float((bits >> 9) | 0x3F800000u) - 1.0f;
}

// 32-bit random bits for flat element index i under partitionable threefry:
// xor-fold of the two output words of block (hi=0, lo=i).
__device__ __forceinline__ uint32_t rbits32(uint32_t k0, uint32_t k1, uint32_t i) {
  uint32_t o0, o1;
  tf2x32(k0, k1, 0u, i, o0, o1);
  return o0 ^ o1;
}

__global__ void __launch_bounds__(256)
aug_pipeline(const int* __restrict__ seq, const int* __restrict__ lens,
             int* __restrict__ out, AugKeys K)
{
  __shared__ int s_seq[NL];
  __shared__ unsigned long long s_key[NL];
  __shared__ float s_u[9];
  __shared__ int s_cnt[4];
  __shared__ int s_rcols[5];
  __shared__ int s_rvals[5];

  const int b = blockIdx.x;
  const int t = threadIdx.x;
  const int l0 = 2 * t, l1 = 2 * t + 1;
  const int len = lens[b];

  const int2 v = reinterpret_cast<const int2*>(seq + (size_t)b * NL)[t];
  s_seq[l0] = v.x;
  s_seq[l1] = v.y;

  // Scalar per-row uniforms: crop start (kc), reorder u1,u2,u3 (B,), u4 (B,5).
  if (t < 9) {
    uint32_t kk0, kk1, f;
    if (t == 0)      { kk0 = K.kc0; kk1 = K.kc1; f = (uint32_t)b; }
    else if (t == 1) { kk0 = K.r10; kk1 = K.r11; f = (uint32_t)b; }
    else if (t == 2) { kk0 = K.r20; kk1 = K.r21; f = (uint32_t)b; }
    else if (t == 3) { kk0 = K.r30; kk1 = K.r31; f = (uint32_t)b; }
    else             { kk0 = K.r40; kk1 = K.r41; f = (uint32_t)b * 5u + (uint32_t)(t - 4); }
    s_u[t] = u01f(rbits32(kk0, kk1, f));
  }

  // ---- mask scores: composite 64-bit key = (score_bits << 9) | idx ----
  const float sc0 = u01f(rbits32(K.km0, K.km1, (uint32_t)b * NL + (uint32_t)l0));
  const float sc1 = u01f(rbits32(K.km0, K.km1, (uint32_t)b * NL + (uint32_t)l1));

  const bool valid0 = (l0 < len) && (v.x != 0);
  const bool valid1 = (l1 < len) && (v.y != 0);
  const unsigned long long INFB = ((unsigned long long)0x7F800000u) << 9;
  const unsigned long long key0 =
      (valid0 ? (((unsigned long long)__float_as_uint(sc0)) << 9) : INFB) | (unsigned)l0;
  const unsigned long long key1 =
      (valid1 ? (((unsigned long long)__float_as_uint(sc1)) << 9) : INFB) | (unsigned)l1;
  s_key[l0] = key0;
  s_key[l1] = key1;

  // n_valid via ballot (4 waves)
  const unsigned long long bal0 = __ballot(valid0);
  const unsigned long long bal1 = __ballot(valid1);
  if ((t & 63) == 0) s_cnt[t >> 6] = __popcll(bal0) + __popcll(bal1);
  __syncthreads();
  const int n_valid = s_cnt[0] + s_cnt[1] + s_cnt[2] + s_cnt[3];

  // ---- bitonic sort of 512 keys (ascending), 256 threads x 1 CE each ----
  for (int k = 2; k <= NL; k <<= 1) {
    for (int j = k >> 1; j > 0; j >>= 1) {
      __syncthreads();
      const int i = ((t & ~(j - 1)) << 1) | (t & (j - 1));
      const int p = i + j;
      const unsigned long long a = s_key[i];
      const unsigned long long c = s_key[p];
      const bool up = ((i & k) == 0);
      if ((a > c) == up) { s_key[i] = c; s_key[p] = a; }
    }
  }
  __syncthreads();

  // ---- mask output ----
  const int n_mask = min(max(1, (int)((float)n_valid * 0.2f)), n_valid);
  const bool apply_m = (len > 1) && (n_valid > 0);
  const unsigned long long T = s_key[(n_mask > 0 ? n_mask : 1) - 1];
  const int m0 = (apply_m && key0 <= T) ? 0 : v.x;  // MASK_TOKEN = 0
  const int m1 = (apply_m && key1 <= T) ? 0 : v.y;
  reinterpret_cast<int2*>(out + (size_t)b * NL)[t] = make_int2(m0, m1);

  // ---- crop output ----
  const float uc = s_u[0];
  const int clen = min(max(3, (int)((float)len * 0.8f)), len);
  const int cmax_start = max(len - clen + 1, 1);
  const int cstart = (int)(uc * (float)cmax_start);
  const bool apply_c = (len > 3);
  int c0, c1;
  if (apply_c) {
    c0 = (l0 < clen) ? s_seq[min(cstart + l0, NL - 1)] : 0;
    c1 = (l1 < clen) ? s_seq[min(cstart + l1, NL - 1)] : 0;
  } else {
    c0 = v.x; c1 = v.y;
  }
  reinterpret_cast<int2*>(out + (size_t)NBL + NB + (size_t)b * NL)[t] = make_int2(c0, c1);

  // ---- reorder: thread 0 computes the 5-slot window in scatter order ----
  if (t == 0) {
    const int max_w = min(n_valid, 5);
    int wsize = 2 + (int)(s_u[1] * (float)max(max_w - 1, 1));
    wsize = min(max(wsize, 2), 5);
    const int rmax_start = max(n_valid - wsize + 1, 1);
    const int rstart = (int)(s_u[2] * (float)rmax_start);
    const bool apply_r = (len > 2) && (s_u[3] <= 0.3f) && (n_valid >= 2);

    int cols[5], items[5];
    float fkeys[5];
    for (int k = 0; k < 5; ++k) {
      cols[k] = min(rstart + k, NL - 1);   // valid_idx is identity (prefix-valid data)
      items[k] = s_seq[cols[k]];
      fkeys[k] = (k < wsize) ? s_u[4 + k] : __int_as_float(0x7F800000);
    }
    // stable argsort of 5 keys (insertion sort)
    int perm[5] = {0, 1, 2, 3, 4};
    for (int a = 1; a < 5; ++a) {
      const int p = perm[a];
      const float kp = fkeys[p];
      int c = a - 1;
      while (c >= 0 && fkeys[perm[c]] > kp) { perm[c + 1] = perm[c]; --c; }
      perm[c + 1] = p;
    }
    for (int k = 0; k < 5; ++k) {
      const int val = (apply_r && k < wsize) ? items[perm[k]] : items[k];
      s_rcols[k] = cols[k];
      s_rvals[k] = val;
    }
  }
  __syncthreads();

  int r0 = v.x, r1 = v.y;
#pragma unroll
  for (int k = 0; k < 5; ++k) {  // ascending k: last duplicate write wins (XLA scatter order)
    if (s_rcols[k] == l0) r0 = s_rvals[k];
    if (s_rcols[k] == l1) r1 = s_rvals[k];
  }
  reinterpret_cast<int2*>(out + 2 * (size_t)NBL + 2 * NB + (size_t)b * NL)[t] = make_int2(r0, r1);

  // ---- lens outputs ----
  if (t == 0) {
    out[(size_t)NBL + b] = len;                             // mask_len
    out[2 * (size_t)NBL + NB + b] = apply_c ? clen : len;   // crop_len
    out[3 * (size_t)NBL + 2 * NB + b] = len;                // reord_len
  }
}

extern "C" void kernel_launch(void* const* d_in, const int* in_sizes, int n_in,
                              void* d_out, int out_size, void* d_ws, size_t ws_size,
                              hipStream_t stream) {
  const int* seq  = (const int*)d_in[0];
  const int* lens = (const int*)d_in[1];
  int* out = (int*)d_out;

  // key(42) = (0, 42). Partitionable (fold-like) split:
  // child i = full threefry block (counts hi=0, lo=i), key = (o0, o1).
  AugKeys K;
  uint32_t kr0, kr1;
  tf2x32(0u, 42u, 0u, 0u, K.km0, K.km1);  // km
  tf2x32(0u, 42u, 0u, 1u, K.kc0, K.kc1);  // kc
  tf2x32(0u, 42u, 0u, 2u, kr0, kr1);      // kr
  tf2x32(kr0, kr1, 0u, 0u, K.r10, K.r11); // k1
  tf2x32(kr0, kr1, 0u, 1u, K.r20, K.r21); // k2
  tf2x32(kr0, kr1, 0u, 2u, K.r30, K.r31); // k3
  tf2x32(kr0, kr1, 0u, 3u, K.r40, K.r41); // k4

  aug_pipeline<<<dim3(NB), dim3(256), 0, stream>>>(seq, lens, out, K);
}

// Round 2
// 111.517 us; speedup vs baseline: 2.3044x; 2.3044x over previous
//
#include <hip/hip_runtime.h>
#include <stdint.h>

// AugmentationPipeline: bit-exact JAX threefry (partitionable path) on device.
// B=32768 rows, L=512. One 256-thread block per row.
// Round 2: bitonic sort (45 staged syncs) -> O(n) radix-select (6 syncs).
// Out layout (int32): mask_seq[B*L] | mask_len[B] | crop_seq[B*L] | crop_len[B]
//                     | reord_seq[B*L] | reord_len[B]

#define NB 32768
#define NL 512
#define NBL (NB * NL)

struct AugKeys {
  uint32_t km0, km1;   // mask key
  uint32_t kc0, kc1;   // crop key
  uint32_t r10, r11;   // reorder k1 (wsize)
  uint32_t r20, r21;   // reorder k2 (start)
  uint32_t r30, r31;   // reorder k3 (apply)
  uint32_t r40, r41;   // reorder k4 (window keys, shape (B,5))
};

__host__ __device__ __forceinline__ uint32_t rotl32(uint32_t x, uint32_t r) {
  return (x << r) | (x >> (32u - r));
}

// Threefry-2x32, 20 rounds (JAX's threefry2x32_p).
__host__ __device__ inline void tf2x32(uint32_t k0, uint32_t k1,
                                       uint32_t x0, uint32_t x1,
                                       uint32_t& o0, uint32_t& o1) {
  const uint32_t ks2 = k0 ^ k1 ^ 0x1BD11BDAu;
#define TFR(r) { x0 += x1; x1 = rotl32(x1, r); x1 ^= x0; }
  x0 += k0; x1 += k1;
  TFR(13u) TFR(15u) TFR(26u) TFR(6u)
  x0 += k1; x1 += ks2 + 1u;
  TFR(17u) TFR(29u) TFR(16u) TFR(24u)
  x0 += ks2; x1 += k0 + 2u;
  TFR(13u) TFR(15u) TFR(26u) TFR(6u)
  x0 += k0; x1 += k1 + 3u;
  TFR(17u) TFR(29u) TFR(16u) TFR(24u)
  x0 += k1; x1 += ks2 + 4u;
  TFR(13u) TFR(15u) TFR(26u) TFR(6u)
  x0 += ks2; x1 += k0 + 5u;
#undef TFR
  o0 = x0; o1 = x1;
}

// JAX uniform(0,1) from 32 random bits.
__device__ __forceinline__ float u01f(uint32_t bits) {
  return __uint_as_float((bits >> 9) | 0x3F800000u) - 1.0f;
}

// 32-bit random bits for flat element index i (partitionable threefry):
// xor-fold of the two output words of block (hi=0, lo=i).
__device__ __forceinline__ uint32_t rbits32(uint32_t k0, uint32_t k1, uint32_t i) {
  uint32_t o0, o1;
  tf2x32(k0, k1, 0u, i, o0, o1);
  return o0 ^ o1;
}

__global__ void __launch_bounds__(256)
aug_pipeline(const int* __restrict__ seq, const int* __restrict__ lens,
             int* __restrict__ out, AugKeys K)
{
  __shared__ int s_seq[NL];
  __shared__ int s_hist[256];
  __shared__ uint32_t s_binkeys[NL];
  __shared__ float s_u[9];
  __shared__ int s_cnt[4];
  __shared__ int s_wsum[4];
  __shared__ int s_rcols[5];
  __shared__ int s_rvals[5];
  __shared__ int s_tbin, s_below, s_nbin;

  const int b = blockIdx.x;
  const int t = threadIdx.x;
  const int lane = t & 63;
  const int wid = t >> 6;
  const int l0 = 2 * t, l1 = 2 * t + 1;
  const int len = lens[b];

  const int2 v = reinterpret_cast<const int2*>(seq + (size_t)b * NL)[t];
  s_seq[l0] = v.x;
  s_seq[l1] = v.y;
  s_hist[t] = 0;
  if (t == 0) { s_nbin = 0; s_tbin = 256; s_below = 0; }

  // Scalar per-row uniforms: crop start (kc), reorder u1,u2,u3 (B,), u4 (B,5).
  if (t < 9) {
    uint32_t kk0, kk1, f;
    if (t == 0)      { kk0 = K.kc0; kk1 = K.kc1; f = (uint32_t)b; }
    else if (t == 1) { kk0 = K.r10; kk1 = K.r11; f = (uint32_t)b; }
    else if (t == 2) { kk0 = K.r20; kk1 = K.r21; f = (uint32_t)b; }
    else if (t == 3) { kk0 = K.r30; kk1 = K.r31; f = (uint32_t)b; }
    else             { kk0 = K.r40; kk1 = K.r41; f = (uint32_t)b * 5u + (uint32_t)(t - 4); }
    s_u[t] = u01f(rbits32(kk0, kk1, f));
  }

  const bool valid0 = (l0 < len) && (v.x != 0);
  const bool valid1 = (l1 < len) && (v.y != 0);
  const unsigned long long bal0 = __ballot(valid0);
  const unsigned long long bal1 = __ballot(valid1);
  if (lane == 0) s_cnt[wid] = __popcll(bal0) + __popcll(bal1);

  __syncthreads();  // (1) s_seq, s_hist=0, s_u, s_cnt ready

  const int n_valid = s_cnt[0] + s_cnt[1] + s_cnt[2] + s_cnt[3];

  // ---- mask score keys: (score_mantissa_bits << 9) | idx, monotone == (score, idx) ----
  // Threefry skipped for whole-waves past len (exec-mask branch).
  uint32_t key0 = 0, key1 = 0;
  if (l0 < len) {
    const uint32_t bits0 = rbits32(K.km0, K.km1, (uint32_t)b * NL + (uint32_t)l0);
    const uint32_t bits1 = rbits32(K.km0, K.km1, (uint32_t)b * NL + (uint32_t)l1);
    key0 = (bits0 & 0xFFFFFE00u) | (uint32_t)l0;
    key1 = (bits1 & 0xFFFFFE00u) | (uint32_t)l1;
    if (valid0) atomicAdd(&s_hist[key0 >> 24], 1);
    if (valid1) atomicAdd(&s_hist[key1 >> 24], 1);
  }

  __syncthreads();  // (2) histogram complete

  // ---- prefix scan over 256 bins (wave shuffle scan + cross-wave base) ----
  const int h = s_hist[t];
  int incl = h;
  #pragma unroll
  for (int d = 1; d < 64; d <<= 1) {
    const int o = __shfl_up(incl, d);
    if (lane >= d) incl += o;
  }
  if (lane == 63) s_wsum[wid] = incl;

  __syncthreads();  // (3) wave sums ready

  int base = 0;
  for (int w = 0; w < wid; ++w) base += s_wsum[w];
  const int e = base + incl - h;  // exclusive prefix: # keys in bins < t
  const int n_mask = min(max(1, (int)((float)n_valid * 0.2f)), n_valid);
  if (h > 0 && e < n_mask && n_mask <= e + h) { s_tbin = t; s_below = e; }

  __syncthreads();  // (4) threshold bin identified

  const int tbin = s_tbin;
  const int below = s_below;
  const int need = n_mask - below;
  if (valid0 && (int)(key0 >> 24) == tbin) {
    const int p = atomicAdd(&s_nbin, 1);
    s_binkeys[p] = key0;
  }
  if (valid1 && (int)(key1 >> 24) == tbin) {
    const int p = atomicAdd(&s_nbin, 1);
    s_binkeys[p] = key1;
  }

  __syncthreads();  // (5) in-bin keys gathered

  const int m = s_nbin;
  const bool apply_m = (len > 1) && (n_valid > 0);
  bool dm0 = false, dm1 = false;
  if (apply_m && valid0) {
    const int bin = (int)(key0 >> 24);
    if (bin < tbin) dm0 = true;
    else if (bin == tbin) {
      int r = 0;
      for (int j = 0; j < m; ++j) r += (s_binkeys[j] < key0);
      dm0 = (r < need);
    }
  }
  if (apply_m && valid1) {
    const int bin = (int)(key1 >> 24);
    if (bin < tbin) dm1 = true;
    else if (bin == tbin) {
      int r = 0;
      for (int j = 0; j < m; ++j) r += (s_binkeys[j] < key1);
      dm1 = (r < need);
    }
  }
  reinterpret_cast<int2*>(out + (size_t)b * NL)[t] =
      make_int2(dm0 ? 0 : v.x, dm1 ? 0 : v.y);  // MASK_TOKEN = 0

  // ---- crop output ----
  const float uc = s_u[0];
  const int clen = min(max(3, (int)((float)len * 0.8f)), len);
  const int cmax_start = max(len - clen + 1, 1);
  const int cstart = (int)(uc * (float)cmax_start);
  const bool apply_c = (len > 3);
  int c0, c1;
  if (apply_c) {
    c0 = (l0 < clen) ? s_seq[min(cstart + l0, NL - 1)] : 0;
    c1 = (l1 < clen) ? s_seq[min(cstart + l1, NL - 1)] : 0;
  } else {
    c0 = v.x; c1 = v.y;
  }
  reinterpret_cast<int2*>(out + (size_t)NBL + NB + (size_t)b * NL)[t] = make_int2(c0, c1);

  // ---- reorder: thread 0 computes the 5-slot window in scatter order ----
  if (t == 0) {
    const int max_w = min(n_valid, 5);
    int wsize = 2 + (int)(s_u[1] * (float)max(max_w - 1, 1));
    wsize = min(max(wsize, 2), 5);
    const int rmax_start = max(n_valid - wsize + 1, 1);
    const int rstart = (int)(s_u[2] * (float)rmax_start);
    const bool apply_r = (len > 2) && (s_u[3] <= 0.3f) && (n_valid >= 2);

    int cols[5], items[5];
    float fkeys[5];
    for (int k = 0; k < 5; ++k) {
      cols[k] = min(rstart + k, NL - 1);   // valid_idx is identity (prefix-valid data)
      items[k] = s_seq[cols[k]];
      fkeys[k] = (k < wsize) ? s_u[4 + k] : __int_as_float(0x7F800000);
    }
    // stable argsort of 5 keys (insertion sort)
    int perm[5] = {0, 1, 2, 3, 4};
    for (int a = 1; a < 5; ++a) {
      const int p = perm[a];
      const float kp = fkeys[p];
      int c = a - 1;
      while (c >= 0 && fkeys[perm[c]] > kp) { perm[c + 1] = perm[c]; --c; }
      perm[c + 1] = p;
    }
    for (int k = 0; k < 5; ++k) {
      const int val = (apply_r && k < wsize) ? items[perm[k]] : items[k];
      s_rcols[k] = cols[k];
      s_rvals[k] = val;
    }
  }
  __syncthreads();  // (6) reorder window ready

  int r0 = v.x, r1 = v.y;
#pragma unroll
  for (int k = 0; k < 5; ++k) {  // ascending k: last duplicate write wins (XLA scatter order)
    if (s_rcols[k] == l0) r0 = s_rvals[k];
    if (s_rcols[k] == l1) r1 = s_rvals[k];
  }
  reinterpret_cast<int2*>(out + 2 * (size_t)NBL + 2 * NB + (size_t)b * NL)[t] = make_int2(r0, r1);

  // ---- lens outputs ----
  if (t == 0) {
    out[(size_t)NBL + b] = len;                             // mask_len
    out[2 * (size_t)NBL + NB + b] = apply_c ? clen : len;   // crop_len
    out[3 * (size_t)NBL + 2 * NB + b] = len;                // reord_len
  }
}

extern "C" void kernel_launch(void* const* d_in, const int* in_sizes, int n_in,
                              void* d_out, int out_size, void* d_ws, size_t ws_size,
                              hipStream_t stream) {
  const int* seq  = (const int*)d_in[0];
  const int* lens = (const int*)d_in[1];
  int* out = (int*)d_out;

  // key(42) = (0, 42). Partitionable (fold-like) split:
  // child i = full threefry block (counts hi=0, lo=i), key = (o0, o1).
  AugKeys K;
  uint32_t kr0, kr1;
  tf2x32(0u, 42u, 0u, 0u, K.km0, K.km1);  // km
  tf2x32(0u, 42u, 0u, 1u, K.kc0, K.kc1);  // kc
  tf2x32(0u, 42u, 0u, 2u, kr0, kr1);      // kr
  tf2x32(kr0, kr1, 0u, 0u, K.r10, K.r11); // k1
  tf2x32(kr0, kr1, 0u, 1u, K.r20, K.r21); // k2
  tf2x32(kr0, kr1, 0u, 2u, K.r30, K.r31); // k3
  tf2x32(kr0, kr1, 0u, 3u, K.r40, K.r41); // k4

  aug_pipeline<<<dim3(NB), dim3(256), 0, stream>>>(seq, lens, out, K);
}

// Round 3
// 89.600 us; speedup vs baseline: 2.8681x; 1.2446x over previous
//
#include <hip/hip_runtime.h>
#include <stdint.h>

// AugmentationPipeline: bit-exact JAX threefry (partitionable path) on device.
// Round 3: 2 rows per 256-thread block (128 thr/row, 4 elem/thr, int4 IO),
// 128-bin radix select, 5 barriers, reorder/crop hoisted for store overlap.
// Out layout (int32): mask_seq[B*L] | mask_len[B] | crop_seq[B*L] | crop_len[B]
//                     | reord_seq[B*L] | reord_len[B]

#define NB 32768
#define NL 512
#define NBL (NB * NL)

struct AugKeys {
  uint32_t km0, km1;   // mask key
  uint32_t kc0, kc1;   // crop key
  uint32_t r10, r11;   // reorder k1 (wsize)
  uint32_t r20, r21;   // reorder k2 (start)
  uint32_t r30, r31;   // reorder k3 (apply)
  uint32_t r40, r41;   // reorder k4 (window keys, shape (B,5))
};

__host__ __device__ __forceinline__ uint32_t rotl32(uint32_t x, uint32_t r) {
  return (x << r) | (x >> (32u - r));
}

// Threefry-2x32, 20 rounds (JAX's threefry2x32_p).
__host__ __device__ inline void tf2x32(uint32_t k0, uint32_t k1,
                                       uint32_t x0, uint32_t x1,
                                       uint32_t& o0, uint32_t& o1) {
  const uint32_t ks2 = k0 ^ k1 ^ 0x1BD11BDAu;
#define TFR(r) { x0 += x1; x1 = rotl32(x1, r); x1 ^= x0; }
  x0 += k0; x1 += k1;
  TFR(13u) TFR(15u) TFR(26u) TFR(6u)
  x0 += k1; x1 += ks2 + 1u;
  TFR(17u) TFR(29u) TFR(16u) TFR(24u)
  x0 += ks2; x1 += k0 + 2u;
  TFR(13u) TFR(15u) TFR(26u) TFR(6u)
  x0 += k0; x1 += k1 + 3u;
  TFR(17u) TFR(29u) TFR(16u) TFR(24u)
  x0 += k1; x1 += ks2 + 4u;
  TFR(13u) TFR(15u) TFR(26u) TFR(6u)
  x0 += ks2; x1 += k0 + 5u;
#undef TFR
  o0 = x0; o1 = x1;
}

// JAX uniform(0,1) from 32 random bits.
__device__ __forceinline__ float u01f(uint32_t bits) {
  return __uint_as_float((bits >> 9) | 0x3F800000u) - 1.0f;
}

// 32-bit random bits for flat element index i (partitionable threefry):
// xor-fold of the two output words of block (hi=0, lo=i).
__device__ __forceinline__ uint32_t rbits32(uint32_t k0, uint32_t k1, uint32_t i) {
  uint32_t o0, o1;
  tf2x32(k0, k1, 0u, i, o0, o1);
  return o0 ^ o1;
}

__global__ void __launch_bounds__(256)
aug_pipeline(const int* __restrict__ seq, const int* __restrict__ lens,
             int* __restrict__ out, AugKeys K)
{
  __shared__ int s_seq[2][NL];
  __shared__ int s_hist[2][128];
  __shared__ uint32_t s_binkeys[2][NL];
  __shared__ float s_u[2][9];
  __shared__ int s_cnt[4];       // per-wave valid counts
  __shared__ int s_wsum[2];      // per-row wave0 scan total
  __shared__ int s_rcols[2][5];
  __shared__ int s_rvals[2][5];
  __shared__ int s_tbin[2], s_below[2], s_nbin[2];

  const int t = threadIdx.x;
  const int g = t >> 7;        // row-in-block (0/1)
  const int u = t & 127;       // thread within row
  const int lane = t & 63;
  const int wid = t >> 6;      // wave id 0..3
  const int hw = wid & 1;      // wave within row half (0/1)
  const int b = blockIdx.x * 2 + g;
  const int len = lens[b];
  const int e0 = u * 4;        // first of this thread's 4 elements

  const int4 v = reinterpret_cast<const int4*>(seq + (size_t)b * NL)[u];
  reinterpret_cast<int4*>(s_seq[g])[u] = v;
  s_hist[g][u] = 0;
  if (u == 0) { s_nbin[g] = 0; s_tbin[g] = 128; s_below[g] = 0; }

  // Per-row uniforms: crop start (kc), reorder u1,u2,u3 (B,), u4 (B,5).
  if (u < 9) {
    uint32_t kk0, kk1, f;
    if (u == 0)      { kk0 = K.kc0; kk1 = K.kc1; f = (uint32_t)b; }
    else if (u == 1) { kk0 = K.r10; kk1 = K.r11; f = (uint32_t)b; }
    else if (u == 2) { kk0 = K.r20; kk1 = K.r21; f = (uint32_t)b; }
    else if (u == 3) { kk0 = K.r30; kk1 = K.r31; f = (uint32_t)b; }
    else             { kk0 = K.r40; kk1 = K.r41; f = (uint32_t)b * 5u + (uint32_t)(u - 4); }
    s_u[g][u] = u01f(rbits32(kk0, kk1, f));
  }

  const int elem[4] = {v.x, v.y, v.z, v.w};
  bool val[4];
  int myc = 0;
#pragma unroll
  for (int i = 0; i < 4; ++i) {
    val[i] = (e0 + i < len) && (elem[i] != 0);
    myc += val[i] ? 1 : 0;
  }
#pragma unroll
  for (int d = 32; d >= 1; d >>= 1) myc += __shfl_down(myc, d);
  if (lane == 0) s_cnt[wid] = myc;

  __syncthreads();  // (1) s_seq, s_hist=0, s_u, s_cnt ready

  const int n_valid = s_cnt[g * 2] + s_cnt[g * 2 + 1];

  // ---- reorder prep (one thread per row), overlaps with everything below ----
  if (u == 0) {
    const int max_w = min(n_valid, 5);
    int wsize = 2 + (int)(s_u[g][1] * (float)max(max_w - 1, 1));
    wsize = min(max(wsize, 2), 5);
    const int rmax_start = max(n_valid - wsize + 1, 1);
    const int rstart = (int)(s_u[g][2] * (float)rmax_start);
    const bool apply_r = (len > 2) && (s_u[g][3] <= 0.3f) && (n_valid >= 2);

    int cols[5], items[5];
    float fkeys[5];
#pragma unroll
    for (int k = 0; k < 5; ++k) {
      cols[k] = min(rstart + k, NL - 1);   // valid_idx is identity (prefix-valid data)
      items[k] = s_seq[g][cols[k]];
      fkeys[k] = (k < wsize) ? s_u[g][4 + k] : __int_as_float(0x7F800000);
    }
    // stable argsort of 5 keys (insertion sort)
    int perm[5] = {0, 1, 2, 3, 4};
    for (int a = 1; a < 5; ++a) {
      const int p = perm[a];
      const float kp = fkeys[p];
      int c = a - 1;
      while (c >= 0 && fkeys[perm[c]] > kp) { perm[c + 1] = perm[c]; --c; }
      perm[c + 1] = p;
    }
#pragma unroll
    for (int k = 0; k < 5; ++k) {
      s_rcols[g][k] = cols[k];
      s_rvals[g][k] = (apply_r && k < wsize) ? items[perm[k]] : items[k];
    }
  }

  // ---- crop output (early: stores drain during select phases) ----
  const float uc = s_u[g][0];
  const int clen = min(max(3, (int)((float)len * 0.8f)), len);
  const int cmax_start = max(len - clen + 1, 1);
  const int cstart = (int)(uc * (float)cmax_start);
  const bool apply_c = (len > 3);
  int c[4];
#pragma unroll
  for (int i = 0; i < 4; ++i) {
    c[i] = apply_c ? ((e0 + i < clen) ? s_seq[g][min(cstart + e0 + i, NL - 1)] : 0)
                   : elem[i];
  }
  reinterpret_cast<int4*>(out + (size_t)NBL + NB + (size_t)b * NL)[u] =
      make_int4(c[0], c[1], c[2], c[3]);

  // ---- mask score keys: (bits & ~0x1FF) | idx, monotone == (score, idx) ----
  uint32_t key[4] = {0u, 0u, 0u, 0u};
  if (e0 < len) {   // whole-wave skip past len
#pragma unroll
    for (int i = 0; i < 4; ++i) {
      const uint32_t bits = rbits32(K.km0, K.km1, (uint32_t)b * NL + (uint32_t)(e0 + i));
      key[i] = (bits & 0xFFFFFE00u) | (uint32_t)(e0 + i);
      if (val[i]) atomicAdd(&s_hist[g][key[i] >> 25], 1);
    }
  }

  __syncthreads();  // (2) histogram complete

  // ---- scan 128 bins with 128 threads (shuffle scan + cross-wave base) ----
  const int h = s_hist[g][u];
  int incl = h;
#pragma unroll
  for (int d = 1; d < 64; d <<= 1) {
    const int o = __shfl_up(incl, d);
    if (lane >= d) incl += o;
  }
  if (hw == 0 && lane == 63) s_wsum[g] = incl;

  __syncthreads();  // (3) wave sums ready

  const int base = hw ? s_wsum[g] : 0;
  const int e_ex = base + incl - h;  // # keys in bins < u
  const int n_mask = min(max(1, (int)((float)n_valid * 0.2f)), n_valid);
  if (h > 0 && e_ex < n_mask && n_mask <= e_ex + h) { s_tbin[g] = u; s_below[g] = e_ex; }

  __syncthreads();  // (4) threshold bin identified

  const int tbin = s_tbin[g];
  const int need = n_mask - s_below[g];
#pragma unroll
  for (int i = 0; i < 4; ++i) {
    if (val[i] && (int)(key[i] >> 25) == tbin) {
      s_binkeys[g][atomicAdd(&s_nbin[g], 1)] = key[i];
    }
  }

  __syncthreads();  // (5) in-bin keys gathered

  const int m = s_nbin[g];
  const bool apply_m = (len > 1) && (n_valid > 0);
  int rk[4] = {0, 0, 0, 0};
  for (int j = 0; j < m; ++j) {
    const uint32_t bk = s_binkeys[g][j];
#pragma unroll
    for (int i = 0; i < 4; ++i) rk[i] += (bk < key[i]) ? 1 : 0;
  }
  int mo[4];
#pragma unroll
  for (int i = 0; i < 4; ++i) {
    const int bin = (int)(key[i] >> 25);
    const bool dm = apply_m && val[i] &&
                    (bin < tbin || (bin == tbin && rk[i] < need));
    mo[i] = dm ? 0 : elem[i];  // MASK_TOKEN = 0
  }
  reinterpret_cast<int4*>(out + (size_t)b * NL)[u] = make_int4(mo[0], mo[1], mo[2], mo[3]);

  // ---- reorder output ----
  int r[4] = {elem[0], elem[1], elem[2], elem[3]};
#pragma unroll
  for (int k = 0; k < 5; ++k) {  // ascending k: last duplicate write wins (XLA scatter order)
    const int rc = s_rcols[g][k];
    const int rv = s_rvals[g][k];
#pragma unroll
    for (int i = 0; i < 4; ++i) if (rc == e0 + i) r[i] = rv;
  }
  reinterpret_cast<int4*>(out + 2 * (size_t)NBL + 2 * NB + (size_t)b * NL)[u] =
      make_int4(r[0], r[1], r[2], r[3]);

  // ---- lens outputs ----
  if (u == 0) {
    out[(size_t)NBL + b] = len;                             // mask_len
    out[2 * (size_t)NBL + NB + b] = apply_c ? clen : len;   // crop_len
    out[3 * (size_t)NBL + 2 * NB + b] = len;                // reord_len
  }
}

extern "C" void kernel_launch(void* const* d_in, const int* in_sizes, int n_in,
                              void* d_out, int out_size, void* d_ws, size_t ws_size,
                              hipStream_t stream) {
  const int* seq  = (const int*)d_in[0];
  const int* lens = (const int*)d_in[1];
  int* out = (int*)d_out;

  // key(42) = (0, 42). Partitionable (fold-like) split:
  // child i = full threefry block (counts hi=0, lo=i), key = (o0, o1).
  AugKeys K;
  uint32_t kr0, kr1;
  tf2x32(0u, 42u, 0u, 0u, K.km0, K.km1);  // km
  tf2x32(0u, 42u, 0u, 1u, K.kc0, K.kc1);  // kc
  tf2x32(0u, 42u, 0u, 2u, kr0, kr1);      // kr
  tf2x32(kr0, kr1, 0u, 0u, K.r10, K.r11); // k1
  tf2x32(kr0, kr1, 0u, 1u, K.r20, K.r21); // k2
  tf2x32(kr0, kr1, 0u, 2u, K.r30, K.r31); // k3
  tf2x32(kr0, kr1, 0u, 3u, K.r40, K.r41); // k4

  aug_pipeline<<<dim3(NB / 2), dim3(256), 0, stream>>>(seq, lens, out, K);
}

// Round 4
// 74.323 us; speedup vs baseline: 3.4576x; 1.2056x over previous
//
#include <hip/hip_runtime.h>
#include <stdint.h>

// AugmentationPipeline: bit-exact JAX threefry (partitionable path) on device.
// Round 4: ONE WAVE PER ROW (64 thr/row, 8 elem/thr), 4 rows per 256-block.
// Zero s_barriers: all row coordination is wave-internal (shuffle/ballot);
// wave-private LDS (hist + bin buffer) ordered by wave_barrier (free).
// Crop gather + reorder window via register shuffles, no s_seq staging.
// Out layout (int32): mask_seq[B*L] | mask_len[B] | crop_seq[B*L] | crop_len[B]
//                     | reord_seq[B*L] | reord_len[B]

#define NB 32768
#define NL 512
#define NBL (NB * NL)

struct AugKeys {
  uint32_t km0, km1;   // mask key
  uint32_t kc0, kc1;   // crop key
  uint32_t r10, r11;   // reorder k1 (wsize)
  uint32_t r20, r21;   // reorder k2 (start)
  uint32_t r30, r31;   // reorder k3 (apply)
  uint32_t r40, r41;   // reorder k4 (window keys, shape (B,5))
};

__host__ __device__ __forceinline__ uint32_t rotl32(uint32_t x, uint32_t r) {
  return (x << r) | (x >> (32u - r));
}

// Threefry-2x32, 20 rounds (JAX's threefry2x32_p).
__host__ __device__ inline void tf2x32(uint32_t k0, uint32_t k1,
                                       uint32_t x0, uint32_t x1,
                                       uint32_t& o0, uint32_t& o1) {
  const uint32_t ks2 = k0 ^ k1 ^ 0x1BD11BDAu;
#define TFR(r) { x0 += x1; x1 = rotl32(x1, r); x1 ^= x0; }
  x0 += k0; x1 += k1;
  TFR(13u) TFR(15u) TFR(26u) TFR(6u)
  x0 += k1; x1 += ks2 + 1u;
  TFR(17u) TFR(29u) TFR(16u) TFR(24u)
  x0 += ks2; x1 += k0 + 2u;
  TFR(13u) TFR(15u) TFR(26u) TFR(6u)
  x0 += k0; x1 += k1 + 3u;
  TFR(17u) TFR(29u) TFR(16u) TFR(24u)
  x0 += k1; x1 += ks2 + 4u;
  TFR(13u) TFR(15u) TFR(26u) TFR(6u)
  x0 += ks2; x1 += k0 + 5u;
#undef TFR
  o0 = x0; o1 = x1;
}

// JAX uniform(0,1) from 32 random bits.
__device__ __forceinline__ float u01f(uint32_t bits) {
  return __uint_as_float((bits >> 9) | 0x3F800000u) - 1.0f;
}

// 32-bit random bits for flat element index i (partitionable threefry):
// xor-fold of the two output words of block (hi=0, lo=i).
__device__ __forceinline__ uint32_t rbits32(uint32_t k0, uint32_t k1, uint32_t i) {
  uint32_t o0, o1;
  tf2x32(k0, k1, 0u, i, o0, o1);
  return o0 ^ o1;
}

// Select e[s] for wave-uniform runtime s with static register accesses only.
#define SEL8(e, s) \
  (((s) & 4) ? (((s) & 2) ? (((s) & 1) ? e[7] : e[6]) : (((s) & 1) ? e[5] : e[4])) \
             : (((s) & 2) ? (((s) & 1) ? e[3] : e[2]) : (((s) & 1) ? e[1] : e[0])))

__global__ void __launch_bounds__(256)
aug_pipeline(const int* __restrict__ seq, const int* __restrict__ lens,
             int* __restrict__ out, AugKeys K)
{
  __shared__ int s_hist[4][128];
  __shared__ uint32_t s_bin[4][NL];

  const int t = threadIdx.x;
  const int w = t >> 6;        // row-in-block (wave id)
  const int l = t & 63;        // lane
  const int b = blockIdx.x * 4 + w;
  const int len = lens[b];
  const int e0 = l * 8;

  const int4 va = reinterpret_cast<const int4*>(seq + (size_t)b * NL)[2 * l];
  const int4 vb = reinterpret_cast<const int4*>(seq + (size_t)b * NL)[2 * l + 1];
  const int elem[8] = {va.x, va.y, va.z, va.w, vb.x, vb.y, vb.z, vb.w};

  // validity + wave-wide valid count
  uint32_t vmask = 0;
  int nv = 0;
#pragma unroll
  for (int i = 0; i < 8; ++i) {
    const bool vi = (e0 + i < len) && (elem[i] != 0);
    vmask |= (uint32_t)vi << i;
    nv += vi ? 1 : 0;
  }
#pragma unroll
  for (int d = 1; d < 64; d <<= 1) nv += __shfl_xor(nv, d);
  const int n_valid = nv;

  // per-row uniforms (lanes 0..8), broadcast via shfl
  float uval = 0.f;
  if (l < 9) {
    uint32_t kk0, kk1, f;
    if (l == 0)      { kk0 = K.kc0; kk1 = K.kc1; f = (uint32_t)b; }
    else if (l == 1) { kk0 = K.r10; kk1 = K.r11; f = (uint32_t)b; }
    else if (l == 2) { kk0 = K.r20; kk1 = K.r21; f = (uint32_t)b; }
    else if (l == 3) { kk0 = K.r30; kk1 = K.r31; f = (uint32_t)b; }
    else             { kk0 = K.r40; kk1 = K.r41; f = (uint32_t)b * 5u + (uint32_t)(l - 4); }
    uval = u01f(rbits32(kk0, kk1, f));
  }
  const float u_c = __shfl(uval, 0);
  const float u_w = __shfl(uval, 1);
  const float u_s = __shfl(uval, 2);
  const float u_a = __shfl(uval, 3);
  float u4[5];
#pragma unroll
  for (int k = 0; k < 5; ++k) u4[k] = __shfl(uval, 4 + k);

  // zero wave-private histogram (LDS ops are in-order per wave)
  s_hist[w][2 * l] = 0;
  s_hist[w][2 * l + 1] = 0;
  __builtin_amdgcn_wave_barrier();

  // ---- mask score keys: (bits & ~0x1FF) | idx, monotone == (score, idx) ----
  uint32_t key[8];
#pragma unroll
  for (int i = 0; i < 8; ++i) {
    const uint32_t bits = rbits32(K.km0, K.km1, (uint32_t)b * NL + (uint32_t)(e0 + i));
    key[i] = (bits & 0xFFFFFE00u) | (uint32_t)(e0 + i);
    if (vmask & (1u << i)) atomicAdd(&s_hist[w][key[i] >> 25], 1);
  }
  __builtin_amdgcn_wave_barrier();

  // ---- 128-bin scan, 2 bins/lane, pure shuffle ----
  const int h0 = s_hist[w][2 * l];
  const int h1 = s_hist[w][2 * l + 1];
  const int pair = h0 + h1;
  int incl = pair;
#pragma unroll
  for (int d = 1; d < 64; d <<= 1) {
    const int o = __shfl_up(incl, d);
    if (l >= d) incl += o;
  }
  const int ex0 = incl - pair;
  const int ex1 = ex0 + h0;
  const int n_mask = min(max(1, (int)((float)n_valid * 0.2f)), n_valid);
  const bool c0 = (h0 > 0) && (ex0 < n_mask) && (n_mask <= ex0 + h0);
  const bool c1 = (h1 > 0) && (ex1 < n_mask) && (n_mask <= ex1 + h1);
  const unsigned long long B0 = __ballot(c0);
  const unsigned long long B1 = __ballot(c1);
  int tbin = -1, below = 0;
  if (B0) {
    const int tl = __ffsll(B0) - 1;
    tbin = 2 * tl; below = __shfl(ex0, tl);
  } else if (B1) {
    const int tl = __ffsll(B1) - 1;
    tbin = 2 * tl + 1; below = __shfl(ex1, tl);
  }
  const int need = n_mask - below;

  // ---- compact in-bin keys into wave-private LDS (ballot-scan offsets) ----
  int cnt = 0;
  bool inb[8];
#pragma unroll
  for (int i = 0; i < 8; ++i) {
    inb[i] = (vmask & (1u << i)) && ((int)(key[i] >> 25) == tbin);
    cnt += inb[i] ? 1 : 0;
  }
  int cincl = cnt;
#pragma unroll
  for (int d = 1; d < 64; d <<= 1) {
    const int o = __shfl_up(cincl, d);
    if (l >= d) cincl += o;
  }
  const int mtot = __shfl(cincl, 63);
  int off = cincl - cnt;
#pragma unroll
  for (int i = 0; i < 8; ++i) {
    if (inb[i]) s_bin[w][off++] = key[i];
  }
  __builtin_amdgcn_wave_barrier();

  // ---- rank within threshold bin + mask output ----
  int rk[8] = {0, 0, 0, 0, 0, 0, 0, 0};
  for (int j = 0; j < mtot; ++j) {
    const uint32_t bk = s_bin[w][j];
#pragma unroll
    for (int i = 0; i < 8; ++i) rk[i] += (bk < key[i]) ? 1 : 0;
  }
  const bool apply_m = (len > 1) && (n_valid > 0);
  int o8[8];
#pragma unroll
  for (int i = 0; i < 8; ++i) {
    const int bin = (int)(key[i] >> 25);
    const bool dm = apply_m && (vmask & (1u << i)) && tbin >= 0 &&
                    (bin < tbin || (bin == tbin && rk[i] < need));
    o8[i] = dm ? 0 : elem[i];  // MASK_TOKEN = 0
  }
  {
    int4* p = reinterpret_cast<int4*>(out + (size_t)b * NL);
    p[2 * l]     = make_int4(o8[0], o8[1], o8[2], o8[3]);
    p[2 * l + 1] = make_int4(o8[4], o8[5], o8[6], o8[7]);
  }

  // ---- crop via register shuffles (sub-slot (cstart+i)&7 is lane-invariant) ----
  const int clen = min(max(3, (int)((float)len * 0.8f)), len);
  const int cms = max(len - clen + 1, 1);
  const int cstart = (int)(u_c * (float)cms);
  const bool apply_c = (len > 3);
  int c8[8];
#pragma unroll
  for (int i = 0; i < 8; ++i) {
    const int s = (cstart + i) & 7;                 // wave-uniform
    const int srcl = (cstart + e0 + i) >> 3;        // per-lane
    const int g = __shfl(SEL8(elem, s), srcl);
    c8[i] = apply_c ? ((e0 + i < clen) ? g : 0) : elem[i];
  }
  {
    int4* p = reinterpret_cast<int4*>(out + (size_t)NBL + NB + (size_t)b * NL);
    p[2 * l]     = make_int4(c8[0], c8[1], c8[2], c8[3]);
    p[2 * l + 1] = make_int4(c8[4], c8[5], c8[6], c8[7]);
  }

  // ---- reorder: all lanes compute window redundantly (registers only) ----
  const int max_w = min(n_valid, 5);
  int wsize = 2 + (int)(u_w * (float)max(max_w - 1, 1));
  wsize = min(max(wsize, 2), 5);
  const int rms = max(n_valid - wsize + 1, 1);
  const int rstart = (int)(u_s * (float)rms);
  const bool apply_r = (len > 2) && (u_a <= 0.3f) && (n_valid >= 2);

  int cols[5], items[5];
  float fk[5];
#pragma unroll
  for (int k = 0; k < 5; ++k) {
    cols[k] = min(rstart + k, NL - 1);              // valid_idx is identity
    const int s = cols[k] & 7;                      // wave-uniform
    items[k] = __shfl(SEL8(elem, s), cols[k] >> 3); // uniform src lane
    fk[k] = (k < wsize) ? u4[k] : __int_as_float(0x7F800000);
  }
  // stable argsort of 5 via ranks (static indexing only)
  int rank5[5];
#pragma unroll
  for (int k = 0; k < 5; ++k) {
    int rr = 0;
#pragma unroll
    for (int j = 0; j < 5; ++j) {
      rr += ((fk[j] < fk[k]) || (fk[j] == fk[k] && j < k)) ? 1 : 0;
    }
    rank5[k] = rr;
  }
  int valk[5];
#pragma unroll
  for (int p = 0; p < 5; ++p) {
    int sh = items[0];
#pragma unroll
    for (int k = 0; k < 5; ++k) if (rank5[k] == p) sh = items[k];
    valk[p] = (apply_r && p < wsize) ? sh : items[p];
  }

  int r8[8] = {elem[0], elem[1], elem[2], elem[3], elem[4], elem[5], elem[6], elem[7]};
#pragma unroll
  for (int k = 0; k < 5; ++k) {  // ascending k: last duplicate write wins (XLA scatter order)
#pragma unroll
    for (int i = 0; i < 8; ++i) if (cols[k] == e0 + i) r8[i] = valk[k];
  }
  {
    int4* p = reinterpret_cast<int4*>(out + 2 * (size_t)NBL + 2 * NB + (size_t)b * NL);
    p[2 * l]     = make_int4(r8[0], r8[1], r8[2], r8[3]);
    p[2 * l + 1] = make_int4(r8[4], r8[5], r8[6], r8[7]);
  }

  // ---- lens outputs ----
  if (l == 0) {
    out[(size_t)NBL + b] = len;                             // mask_len
    out[2 * (size_t)NBL + NB + b] = apply_c ? clen : len;   // crop_len
    out[3 * (size_t)NBL + 2 * NB + b] = len;                // reord_len
  }
}

extern "C" void kernel_launch(void* const* d_in, const int* in_sizes, int n_in,
                              void* d_out, int out_size, void* d_ws, size_t ws_size,
                              hipStream_t stream) {
  const int* seq  = (const int*)d_in[0];
  const int* lens = (const int*)d_in[1];
  int* out = (int*)d_out;

  // key(42) = (0, 42). Partitionable (fold-like) split:
  // child i = full threefry block (counts hi=0, lo=i), key = (o0, o1).
  AugKeys K;
  uint32_t kr0, kr1;
  tf2x32(0u, 42u, 0u, 0u, K.km0, K.km1);  // km
  tf2x32(0u, 42u, 0u, 1u, K.kc0, K.kc1);  // kc
  tf2x32(0u, 42u, 0u, 2u, kr0, kr1);      // kr
  tf2x32(kr0, kr1, 0u, 0u, K.r10, K.r11); // k1
  tf2x32(kr0, kr1, 0u, 1u, K.r20, K.r21); // k2
  tf2x32(kr0, kr1, 0u, 2u, K.r30, K.r31); // k3
  tf2x32(kr0, kr1, 0u, 3u, K.r40, K.r41); // k4

  aug_pipeline<<<dim3(NB / 4), dim3(256), 0, stream>>>(seq, lens, out, K);
}

// Round 5
// 72.483 us; speedup vs baseline: 3.5454x; 1.0254x over previous
//
#include <hip/hip_runtime.h>
#include <stdint.h>

// AugmentationPipeline: bit-exact JAX threefry (partitionable path) on device.
// Round 5: STRIDED threefry with wave-uniform chunk skip (pos = it*64 + lane;
// chunks with it*64 >= len branch away => ~44% of threefry eliminated on avg).
// Contiguous int4 I/O kept; validity redistributed contiguous->strided via an
// LDS byte-mask, mask decisions redistributed strided->contiguous via per-chunk
// ballots stored in LDS. One wave per row, zero s_barriers.
// Out layout (int32): mask_seq[B*L] | mask_len[B] | crop_seq[B*L] | crop_len[B]
//                     | reord_seq[B*L] | reord_len[B]

#define NB 32768
#define NL 512
#define NBL (NB * NL)

struct AugKeys {
  uint32_t km0, km1;   // mask key
  uint32_t kc0, kc1;   // crop key
  uint32_t r10, r11;   // reorder k1 (wsize)
  uint32_t r20, r21;   // reorder k2 (start)
  uint32_t r30, r31;   // reorder k3 (apply)
  uint32_t r40, r41;   // reorder k4 (window keys, shape (B,5))
};

__host__ __device__ __forceinline__ uint32_t rotl32(uint32_t x, uint32_t r) {
  return (x << r) | (x >> (32u - r));
}

// Threefry-2x32, 20 rounds (JAX's threefry2x32_p).
__host__ __device__ inline void tf2x32(uint32_t k0, uint32_t k1,
                                       uint32_t x0, uint32_t x1,
                                       uint32_t& o0, uint32_t& o1) {
  const uint32_t ks2 = k0 ^ k1 ^ 0x1BD11BDAu;
#define TFR(r) { x0 += x1; x1 = rotl32(x1, r); x1 ^= x0; }
  x0 += k0; x1 += k1;
  TFR(13u) TFR(15u) TFR(26u) TFR(6u)
  x0 += k1; x1 += ks2 + 1u;
  TFR(17u) TFR(29u) TFR(16u) TFR(24u)
  x0 += ks2; x1 += k0 + 2u;
  TFR(13u) TFR(15u) TFR(26u) TFR(6u)
  x0 += k0; x1 += k1 + 3u;
  TFR(17u) TFR(29u) TFR(16u) TFR(24u)
  x0 += k1; x1 += ks2 + 4u;
  TFR(13u) TFR(15u) TFR(26u) TFR(6u)
  x0 += ks2; x1 += k0 + 5u;
#undef TFR
  o0 = x0; o1 = x1;
}

// JAX uniform(0,1) from 32 random bits.
__device__ __forceinline__ float u01f(uint32_t bits) {
  return __uint_as_float((bits >> 9) | 0x3F800000u) - 1.0f;
}

// 32-bit random bits for flat element index i (partitionable threefry):
// xor-fold of the two output words of block (hi=0, lo=i).
__device__ __forceinline__ uint32_t rbits32(uint32_t k0, uint32_t k1, uint32_t i) {
  uint32_t o0, o1;
  tf2x32(k0, k1, 0u, i, o0, o1);
  return o0 ^ o1;
}

// Select e[s] for runtime s with static register accesses only.
#define SEL8(e, s) \
  (((s) & 4) ? (((s) & 2) ? (((s) & 1) ? e[7] : e[6]) : (((s) & 1) ? e[5] : e[4])) \
             : (((s) & 2) ? (((s) & 1) ? e[3] : e[2]) : (((s) & 1) ? e[1] : e[0])))

__global__ void __launch_bounds__(256)
aug_pipeline(const int* __restrict__ seq, const int* __restrict__ lens,
             int* __restrict__ out, AugKeys K)
{
  __shared__ int s_hist[4][128];
  __shared__ uint32_t s_bin[4][NL];
  __shared__ int s_vb[4][64];                 // per-contiguous-lane validity byte
  __shared__ unsigned long long s_D[4][8];    // per-chunk decision ballots
  __shared__ int s_nbin[4];

  const int t = threadIdx.x;
  const int w = t >> 6;        // row-in-block (wave id)
  const int l = t & 63;        // lane
  const int b = blockIdx.x * 4 + w;
  const int len = lens[b];     // wave-uniform
  const int e0 = l * 8;

  const int4 va = reinterpret_cast<const int4*>(seq + (size_t)b * NL)[2 * l];
  const int4 vb = reinterpret_cast<const int4*>(seq + (size_t)b * NL)[2 * l + 1];
  const int elem[8] = {va.x, va.y, va.z, va.w, vb.x, vb.y, vb.z, vb.w};

  // per-row uniforms (lanes 0..8) -- overlaps the global-load latency
  float uval = 0.f;
  if (l < 9) {
    uint32_t kk0, kk1, f;
    if (l == 0)      { kk0 = K.kc0; kk1 = K.kc1; f = (uint32_t)b; }
    else if (l == 1) { kk0 = K.r10; kk1 = K.r11; f = (uint32_t)b; }
    else if (l == 2) { kk0 = K.r20; kk1 = K.r21; f = (uint32_t)b; }
    else if (l == 3) { kk0 = K.r30; kk1 = K.r31; f = (uint32_t)b; }
    else             { kk0 = K.r40; kk1 = K.r41; f = (uint32_t)b * 5u + (uint32_t)(l - 4); }
    uval = u01f(rbits32(kk0, kk1, f));
  }
  const float u_c = __shfl(uval, 0);
  const float u_w = __shfl(uval, 1);
  const float u_s = __shfl(uval, 2);
  const float u_a = __shfl(uval, 3);
  float u4[5];
#pragma unroll
  for (int k = 0; k < 5; ++k) u4[k] = __shfl(uval, 4 + k);

  // contiguous validity byte + n_valid via ballots (scalar pipe)
  bool val[8];
  int vbyte = 0;
#pragma unroll
  for (int i = 0; i < 8; ++i) {
    val[i] = (e0 + i < len) && (elem[i] != 0);
    vbyte |= (val[i] ? 1 : 0) << i;
  }
  int n_valid = 0;
#pragma unroll
  for (int i = 0; i < 8; ++i) n_valid += (int)__popcll(__ballot(val[i]));

  // init wave-private LDS
  s_hist[w][2 * l] = 0;
  s_hist[w][2 * l + 1] = 0;
  s_vb[w][l] = vbyte;
  if (l == 0) s_nbin[w] = 0;
  __builtin_amdgcn_wave_barrier();

  // ---- pass A: strided threefry + histogram; chunks past len skipped ----
  // key = (bits & ~0x1FF) | pos : monotone == (score, idx), unique.
  uint32_t kk[8];
  uint32_t vsm = 0;  // strided validity bits (bit it)
#pragma unroll
  for (int it = 0; it < 8; ++it) {
    if ((it << 6) < len) {                     // wave-uniform skip
      const int pos = (it << 6) + l;
      const uint32_t bits = rbits32(K.km0, K.km1, (uint32_t)b * NL + (uint32_t)pos);
      kk[it] = (bits & 0xFFFFFE00u) | (uint32_t)pos;
      const int vb8 = s_vb[w][(it << 3) + (l >> 3)];   // broadcast read
      const bool vs = (vb8 >> (l & 7)) & 1;
      if (vs) {
        atomicAdd(&s_hist[w][kk[it] >> 25], 1);
        vsm |= 1u << it;
      }
    }
  }
  __builtin_amdgcn_wave_barrier();

  // ---- 128-bin scan, 2 bins/lane, pure shuffle ----
  const int h0 = s_hist[w][2 * l];
  const int h1 = s_hist[w][2 * l + 1];
  const int pair = h0 + h1;
  int incl = pair;
#pragma unroll
  for (int d = 1; d < 64; d <<= 1) {
    const int o = __shfl_up(incl, d);
    if (l >= d) incl += o;
  }
  const int ex0 = incl - pair;
  const int ex1 = ex0 + h0;
  const int n_mask = min(max(1, (int)((float)n_valid * 0.2f)), n_valid);
  const bool c0 = (h0 > 0) && (ex0 < n_mask) && (n_mask <= ex0 + h0);
  const bool c1 = (h1 > 0) && (ex1 < n_mask) && (n_mask <= ex1 + h1);
  const unsigned long long B0 = __ballot(c0);
  const unsigned long long B1 = __ballot(c1);
  int tbin = -1, below = 0;
  if (B0) {
    const int tl = __ffsll(B0) - 1;
    tbin = 2 * tl; below = __shfl(ex0, tl);
  } else if (B1) {
    const int tl = __ffsll(B1) - 1;
    tbin = 2 * tl + 1; below = __shfl(ex1, tl);
  }
  const int need = n_mask - below;

  // ---- pass B: compact in-bin keys (atomic append; order irrelevant) ----
#pragma unroll
  for (int it = 0; it < 8; ++it) {
    if ((it << 6) < len) {
      if (((vsm >> it) & 1) && (int)(kk[it] >> 25) == tbin) {
        s_bin[w][atomicAdd(&s_nbin[w], 1)] = kk[it];
      }
    }
  }
  __builtin_amdgcn_wave_barrier();
  const int mtot = s_nbin[w];
  const bool apply_m = (len > 1) && (n_valid > 0);

  // ---- pass C: rank + decision ballot per chunk ----
#pragma unroll
  for (int it = 0; it < 8; ++it) {
    if ((it << 6) < len) {
      int rk = 0;
      for (int j = 0; j < mtot; ++j) rk += (s_bin[w][j] < kk[it]) ? 1 : 0;
      const int bin = (int)(kk[it] >> 25);
      const bool dm = apply_m && ((vsm >> it) & 1) && tbin >= 0 &&
                      (bin < tbin || (bin == tbin && rk < need));
      const unsigned long long Dm = __ballot(dm);
      if (l == 0) s_D[w][it] = Dm;
    }
  }
  __builtin_amdgcn_wave_barrier();

  // ---- mask output: contiguous lane extracts its 8 decision bits ----
  const unsigned long long Dword = s_D[w][l >> 3];      // broadcast read
  const uint32_t dbyte = (uint32_t)(Dword >> (8 * (l & 7))) & 0xFFu;
  int o8[8];
#pragma unroll
  for (int i = 0; i < 8; ++i) {
    o8[i] = (val[i] && ((dbyte >> i) & 1)) ? 0 : elem[i];  // MASK_TOKEN = 0
  }
  {
    int4* p = reinterpret_cast<int4*>(out + (size_t)b * NL);
    p[2 * l]     = make_int4(o8[0], o8[1], o8[2], o8[3]);
    p[2 * l + 1] = make_int4(o8[4], o8[5], o8[6], o8[7]);
  }

  // ---- crop via register shuffles (sub-slot (cstart+i)&7 is wave-uniform) ----
  const int clen = min(max(3, (int)((float)len * 0.8f)), len);
  const int cms = max(len - clen + 1, 1);
  const int cstart = (int)(u_c * (float)cms);
  const bool apply_c = (len > 3);
  int c8[8];
#pragma unroll
  for (int i = 0; i < 8; ++i) {
    const int s = (cstart + i) & 7;                 // wave-uniform
    const int srcl = (cstart + e0 + i) >> 3;        // per-lane
    const int g = __shfl(SEL8(elem, s), srcl);
    c8[i] = apply_c ? ((e0 + i < clen) ? g : 0) : elem[i];
  }
  {
    int4* p = reinterpret_cast<int4*>(out + (size_t)NBL + NB + (size_t)b * NL);
    p[2 * l]     = make_int4(c8[0], c8[1], c8[2], c8[3]);
    p[2 * l + 1] = make_int4(c8[4], c8[5], c8[6], c8[7]);
  }

  // ---- reorder: all lanes compute window redundantly (registers only) ----
  const int max_w = min(n_valid, 5);
  int wsize = 2 + (int)(u_w * (float)max(max_w - 1, 1));
  wsize = min(max(wsize, 2), 5);
  const int rms = max(n_valid - wsize + 1, 1);
  const int rstart = (int)(u_s * (float)rms);
  const bool apply_r = (len > 2) && (u_a <= 0.3f) && (n_valid >= 2);

  int cols[5], items[5];
  float fk[5];
#pragma unroll
  for (int k = 0; k < 5; ++k) {
    cols[k] = min(rstart + k, NL - 1);              // valid_idx is identity
    const int s = cols[k] & 7;                      // wave-uniform
    items[k] = __shfl(SEL8(elem, s), cols[k] >> 3); // uniform src lane
    fk[k] = (k < wsize) ? u4[k] : __int_as_float(0x7F800000);
  }
  // stable argsort of 5 via ranks (static indexing only)
  int rank5[5];
#pragma unroll
  for (int k = 0; k < 5; ++k) {
    int rr = 0;
#pragma unroll
    for (int j = 0; j < 5; ++j) {
      rr += ((fk[j] < fk[k]) || (fk[j] == fk[k] && j < k)) ? 1 : 0;
    }
    rank5[k] = rr;
  }
  int valk[5];
#pragma unroll
  for (int p = 0; p < 5; ++p) {
    int sh = items[0];
#pragma unroll
    for (int k = 0; k < 5; ++k) if (rank5[k] == p) sh = items[k];
    valk[p] = (apply_r && p < wsize) ? sh : items[p];
  }

  int r8[8] = {elem[0], elem[1], elem[2], elem[3], elem[4], elem[5], elem[6], elem[7]};
#pragma unroll
  for (int k = 0; k < 5; ++k) {  // ascending k: last duplicate write wins (XLA scatter order)
#pragma unroll
    for (int i = 0; i < 8; ++i) if (cols[k] == e0 + i) r8[i] = valk[k];
  }
  {
    int4* p = reinterpret_cast<int4*>(out + 2 * (size_t)NBL + 2 * NB + (size_t)b * NL);
    p[2 * l]     = make_int4(r8[0], r8[1], r8[2], r8[3]);
    p[2 * l + 1] = make_int4(r8[4], r8[5], r8[6], r8[7]);
  }

  // ---- lens outputs ----
  if (l == 0) {
    out[(size_t)NBL + b] = len;                             // mask_len
    out[2 * (size_t)NBL + NB + b] = apply_c ? clen : len;   // crop_len
    out[3 * (size_t)NBL + 2 * NB + b] = len;                // reord_len
  }
}

extern "C" void kernel_launch(void* const* d_in, const int* in_sizes, int n_in,
                              void* d_out, int out_size, void* d_ws, size_t ws_size,
                              hipStream_t stream) {
  const int* seq  = (const int*)d_in[0];
  const int* lens = (const int*)d_in[1];
  int* out = (int*)d_out;

  // key(42) = (0, 42). Partitionable (fold-like) split:
  // child i = full threefry block (counts hi=0, lo=i), key = (o0, o1).
  AugKeys K;
  uint32_t kr0, kr1;
  tf2x32(0u, 42u, 0u, 0u, K.km0, K.km1);  // km
  tf2x32(0u, 42u, 0u, 1u, K.kc0, K.kc1);  // kc
  tf2x32(0u, 42u, 0u, 2u, kr0, kr1);      // kr
  tf2x32(kr0, kr1, 0u, 0u, K.r10, K.r11); // k1
  tf2x32(kr0, kr1, 0u, 1u, K.r20, K.r21); // k2
  tf2x32(kr0, kr1, 0u, 2u, K.r30, K.r31); // k3
  tf2x32(kr0, kr1, 0u, 3u, K.r40, K.r41); // k4

  aug_pipeline<<<dim3(NB / 4), dim3(256), 0, stream>>>(seq, lens, out, K);
}

// Round 6
// 63.530 us; speedup vs baseline: 4.0450x; 1.1409x over previous
//
#include <hip/hip_runtime.h>
#include <stdint.h>

// AugmentationPipeline: bit-exact JAX threefry (partitionable path) on device.
// Round 6: mask path fully STRIDED end-to-end (strided loads, strided dword
// stores) -- no contiguous<->strided redistribution LDS at all. Crop/reorder
// (register-shuffle, LDS-free) computed and stored FIRST so stores drain
// during the select phase. Scalarized len/n_valid (s_cbranch chunk skip).
// One wave per row, zero s_barriers; wave-private LDS hist+bin only.
// Out layout (int32): mask_seq[B*L] | mask_len[B] | crop_seq[B*L] | crop_len[B]
//                     | reord_seq[B*L] | reord_len[B]

#define NB 32768
#define NL 512
#define NBL (NB * NL)

struct AugKeys {
  uint32_t km0, km1;   // mask key
  uint32_t kc0, kc1;   // crop key
  uint32_t r10, r11;   // reorder k1 (wsize)
  uint32_t r20, r21;   // reorder k2 (start)
  uint32_t r30, r31;   // reorder k3 (apply)
  uint32_t r40, r41;   // reorder k4 (window keys, shape (B,5))
};

__host__ __device__ __forceinline__ uint32_t rotl32(uint32_t x, uint32_t r) {
  return (x << r) | (x >> (32u - r));
}

// Threefry-2x32, 20 rounds (JAX's threefry2x32_p).
__host__ __device__ inline void tf2x32(uint32_t k0, uint32_t k1,
                                       uint32_t x0, uint32_t x1,
                                       uint32_t& o0, uint32_t& o1) {
  const uint32_t ks2 = k0 ^ k1 ^ 0x1BD11BDAu;
#define TFR(r) { x0 += x1; x1 = rotl32(x1, r); x1 ^= x0; }
  x0 += k0; x1 += k1;
  TFR(13u) TFR(15u) TFR(26u) TFR(6u)
  x0 += k1; x1 += ks2 + 1u;
  TFR(17u) TFR(29u) TFR(16u) TFR(24u)
  x0 += ks2; x1 += k0 + 2u;
  TFR(13u) TFR(15u) TFR(26u) TFR(6u)
  x0 += k0; x1 += k1 + 3u;
  TFR(17u) TFR(29u) TFR(16u) TFR(24u)
  x0 += k1; x1 += ks2 + 4u;
  TFR(13u) TFR(15u) TFR(26u) TFR(6u)
  x0 += ks2; x1 += k0 + 5u;
#undef TFR
  o0 = x0; o1 = x1;
}

// JAX uniform(0,1) from 32 random bits.
__device__ __forceinline__ float u01f(uint32_t bits) {
  return __uint_as_float((bits >> 9) | 0x3F800000u) - 1.0f;
}

// 32-bit random bits for flat element index i (partitionable threefry):
// xor-fold of the two output words of block (hi=0, lo=i).
__device__ __forceinline__ uint32_t rbits32(uint32_t k0, uint32_t k1, uint32_t i) {
  uint32_t o0, o1;
  tf2x32(k0, k1, 0u, i, o0, o1);
  return o0 ^ o1;
}

// Select e[s] for wave-uniform runtime s with static register accesses only.
#define SEL8(e, s) \
  (((s) & 4) ? (((s) & 2) ? (((s) & 1) ? e[7] : e[6]) : (((s) & 1) ? e[5] : e[4])) \
             : (((s) & 2) ? (((s) & 1) ? e[3] : e[2]) : (((s) & 1) ? e[1] : e[0])))

__global__ void __launch_bounds__(256)
aug_pipeline(const int* __restrict__ seq, const int* __restrict__ lens,
             int* __restrict__ out, AugKeys K)
{
  __shared__ int s_hist[4][128];
  __shared__ uint32_t s_bin[4][NL];
  __shared__ int s_nbin[4];

  const int t = threadIdx.x;
  const int w = t >> 6;        // row-in-block (wave id)
  const int l = t & 63;        // lane
  const int b = blockIdx.x * 4 + w;
  const int len = __builtin_amdgcn_readfirstlane(lens[b]);   // wave-uniform scalar
  const int e0 = l * 8;
  const int* rowp = seq + (size_t)b * NL;

  // strided loads (mask path): es[it] = seq[b*512 + it*64 + l]
  int es[8];
#pragma unroll
  for (int it = 0; it < 8; ++it) es[it] = rowp[(it << 6) + l];

  // contiguous load (crop/reorder path; L1-hot, same row)
  const int4 va = reinterpret_cast<const int4*>(rowp)[2 * l];
  const int4 vb = reinterpret_cast<const int4*>(rowp)[2 * l + 1];
  const int elem[8] = {va.x, va.y, va.z, va.w, vb.x, vb.y, vb.z, vb.w};

  // per-row uniforms (lanes 0..8), broadcast via shfl
  float uval = 0.f;
  if (l < 9) {
    uint32_t kk0, kk1, f;
    if (l == 0)      { kk0 = K.kc0; kk1 = K.kc1; f = (uint32_t)b; }
    else if (l == 1) { kk0 = K.r10; kk1 = K.r11; f = (uint32_t)b; }
    else if (l == 2) { kk0 = K.r20; kk1 = K.r21; f = (uint32_t)b; }
    else if (l == 3) { kk0 = K.r30; kk1 = K.r31; f = (uint32_t)b; }
    else             { kk0 = K.r40; kk1 = K.r41; f = (uint32_t)b * 5u + (uint32_t)(l - 4); }
    uval = u01f(rbits32(kk0, kk1, f));
  }
  const float u_c = __shfl(uval, 0);
  const float u_w = __shfl(uval, 1);
  const float u_s = __shfl(uval, 2);
  const float u_a = __shfl(uval, 3);
  float u4[5];
#pragma unroll
  for (int k = 0; k < 5; ++k) u4[k] = __shfl(uval, 4 + k);

  // strided validity + n_valid (ballot/popcount, scalar pipe)
  uint32_t vsm = 0;
  int nv = 0;
#pragma unroll
  for (int it = 0; it < 8; ++it) {
    const bool vs = ((it << 6) + l < len) && (es[it] != 0);
    vsm |= (uint32_t)vs << it;
    nv += (int)__popcll(__ballot(vs));
  }
  const int n_valid = __builtin_amdgcn_readfirstlane(nv);

  // ---- crop (LDS-free, register shuffles) computed + stored EARLY ----
  const int clen = min(max(3, (int)((float)len * 0.8f)), len);
  const int cms = max(len - clen + 1, 1);
  const int cstart = (int)(u_c * (float)cms);
  const bool apply_c = (len > 3);
  {
    int c8[8];
#pragma unroll
    for (int i = 0; i < 8; ++i) {
      const int s = (cstart + i) & 7;                 // wave-uniform
      const int srcl = (cstart + e0 + i) >> 3;        // per-lane
      const int g = __shfl(SEL8(elem, s), srcl);
      c8[i] = apply_c ? ((e0 + i < clen) ? g : 0) : elem[i];
    }
    int4* p = reinterpret_cast<int4*>(out + (size_t)NBL + NB + (size_t)b * NL);
    p[2 * l]     = make_int4(c8[0], c8[1], c8[2], c8[3]);
    p[2 * l + 1] = make_int4(c8[4], c8[5], c8[6], c8[7]);
  }

  // ---- lens outputs (early) ----
  if (l == 0) {
    out[(size_t)NBL + b] = len;                             // mask_len
    out[2 * (size_t)NBL + NB + b] = apply_c ? clen : len;   // crop_len
    out[3 * (size_t)NBL + 2 * NB + b] = len;                // reord_len
  }

  // ---- reorder (LDS-free) computed + stored EARLY ----
  {
    const int max_w = min(n_valid, 5);
    int wsize = 2 + (int)(u_w * (float)max(max_w - 1, 1));
    wsize = min(max(wsize, 2), 5);
    const int rms = max(n_valid - wsize + 1, 1);
    const int rstart = (int)(u_s * (float)rms);
    const bool apply_r = (len > 2) && (u_a <= 0.3f) && (n_valid >= 2);

    int cols[5], items[5];
    float fk[5];
#pragma unroll
    for (int k = 0; k < 5; ++k) {
      cols[k] = min(rstart + k, NL - 1);              // valid_idx is identity
      const int s = cols[k] & 7;                      // wave-uniform
      items[k] = __shfl(SEL8(elem, s), cols[k] >> 3); // uniform src lane
      fk[k] = (k < wsize) ? u4[k] : __int_as_float(0x7F800000);
    }
    // stable argsort of 5 via ranks (static indexing only)
    int rank5[5];
#pragma unroll
    for (int k = 0; k < 5; ++k) {
      int rr = 0;
#pragma unroll
      for (int j = 0; j < 5; ++j) {
        rr += ((fk[j] < fk[k]) || (fk[j] == fk[k] && j < k)) ? 1 : 0;
      }
      rank5[k] = rr;
    }
    int valk[5];
#pragma unroll
    for (int p = 0; p < 5; ++p) {
      int sh = items[0];
#pragma unroll
      for (int k = 0; k < 5; ++k) if (rank5[k] == p) sh = items[k];
      valk[p] = (apply_r && p < wsize) ? sh : items[p];
    }

    int r8[8] = {elem[0], elem[1], elem[2], elem[3], elem[4], elem[5], elem[6], elem[7]};
#pragma unroll
    for (int k = 0; k < 5; ++k) {  // ascending k: last dup write wins (XLA scatter order)
#pragma unroll
      for (int i = 0; i < 8; ++i) if (cols[k] == e0 + i) r8[i] = valk[k];
    }
    int4* p = reinterpret_cast<int4*>(out + 2 * (size_t)NBL + 2 * NB + (size_t)b * NL);
    p[2 * l]     = make_int4(r8[0], r8[1], r8[2], r8[3]);
    p[2 * l + 1] = make_int4(r8[4], r8[5], r8[6], r8[7]);
  }

  // ---- init wave-private LDS ----
  s_hist[w][2 * l] = 0;
  s_hist[w][2 * l + 1] = 0;
  if (l == 0) s_nbin[w] = 0;
  __builtin_amdgcn_wave_barrier();

  // ---- pass A: strided threefry + histogram; chunks past len skipped (scalar) ----
  // key = (bits & ~0x1FF) | pos : monotone == (score, idx), unique.
  uint32_t kk[8] = {0u, 0u, 0u, 0u, 0u, 0u, 0u, 0u};
#pragma unroll
  for (int it = 0; it < 8; ++it) {
    if ((it << 6) < len) {                     // scalar skip
      const int pos = (it << 6) + l;
      const uint32_t bits = rbits32(K.km0, K.km1, (uint32_t)b * NL + (uint32_t)pos);
      kk[it] = (bits & 0xFFFFFE00u) | (uint32_t)pos;
      if ((vsm >> it) & 1) atomicAdd(&s_hist[w][kk[it] >> 25], 1);
    }
  }
  __builtin_amdgcn_wave_barrier();

  // ---- 128-bin scan, 2 bins/lane, pure shuffle ----
  const int h0 = s_hist[w][2 * l];
  const int h1 = s_hist[w][2 * l + 1];
  const int pair = h0 + h1;
  int incl = pair;
#pragma unroll
  for (int d = 1; d < 64; d <<= 1) {
    const int o = __shfl_up(incl, d);
    if (l >= d) incl += o;
  }
  const int ex0 = incl - pair;
  const int ex1 = ex0 + h0;
  const int n_mask = min(max(1, (int)((float)n_valid * 0.2f)), n_valid);
  const bool c0 = (h0 > 0) && (ex0 < n_mask) && (n_mask <= ex0 + h0);
  const bool c1 = (h1 > 0) && (ex1 < n_mask) && (n_mask <= ex1 + h1);
  const unsigned long long B0 = __ballot(c0);
  const unsigned long long B1 = __ballot(c1);
  int tbin = -1, below = 0;
  if (B0) {
    const int tl = __ffsll(B0) - 1;
    tbin = 2 * tl; below = __shfl(ex0, tl);
  } else if (B1) {
    const int tl = __ffsll(B1) - 1;
    tbin = 2 * tl + 1; below = __shfl(ex1, tl);
  }
  const int need = n_mask - below;

  // ---- pass B: compact in-bin keys (atomic append; order irrelevant) ----
  // vsm bit is 0 for pos >= len, so no extra chunk guard needed.
#pragma unroll
  for (int it = 0; it < 8; ++it) {
    if (((vsm >> it) & 1) && (int)(kk[it] >> 25) == tbin) {
      s_bin[w][atomicAdd(&s_nbin[w], 1)] = kk[it];
    }
  }
  __builtin_amdgcn_wave_barrier();
  const int mtot = s_nbin[w];

  // ---- single rank pass over the threshold bin (broadcast LDS reads) ----
  int rk[8] = {0, 0, 0, 0, 0, 0, 0, 0};
  for (int j = 0; j < mtot; ++j) {
    const uint32_t bk = s_bin[w][j];
#pragma unroll
    for (int it = 0; it < 8; ++it) rk[it] += (bk < kk[it]) ? 1 : 0;
  }

  // ---- mask output: strided dword stores (coalesced 256B per instruction) ----
  const bool apply_m = (len > 1) && (n_valid > 0);
  int* mout = out + (size_t)b * NL;
#pragma unroll
  for (int it = 0; it < 8; ++it) {
    const int bin = (int)(kk[it] >> 25);
    const bool dm = apply_m && ((vsm >> it) & 1) &&
                    (bin < tbin || (bin == tbin && rk[it] < need));
    mout[(it << 6) + l] = dm ? 0 : es[it];   // MASK_TOKEN = 0
  }
}

extern "C" void kernel_launch(void* const* d_in, const int* in_sizes, int n_in,
                              void* d_out, int out_size, void* d_ws, size_t ws_size,
                              hipStream_t stream) {
  const int* seq  = (const int*)d_in[0];
  const int* lens = (const int*)d_in[1];
  int* out = (int*)d_out;

  // key(42) = (0, 42). Partitionable (fold-like) split:
  // child i = full threefry block (counts hi=0, lo=i), key = (o0, o1).
  AugKeys K;
  uint32_t kr0, kr1;
  tf2x32(0u, 42u, 0u, 0u, K.km0, K.km1);  // km
  tf2x32(0u, 42u, 0u, 1u, K.kc0, K.kc1);  // kc
  tf2x32(0u, 42u, 0u, 2u, kr0, kr1);      // kr
  tf2x32(kr0, kr1, 0u, 0u, K.r10, K.r11); // k1
  tf2x32(kr0, kr1, 0u, 1u, K.r20, K.r21); // k2
  tf2x32(kr0, kr1, 0u, 2u, K.r30, K.r31); // k3
  tf2x32(kr0, kr1, 0u, 3u, K.r40, K.r41); // k4

  aug_pipeline<<<dim3(NB / 4), dim3(256), 0, stream>>>(seq, lens, out, K);
}

// Round 7
// 60.176 us; speedup vs baseline: 4.2705x; 1.0557x over previous
//
#include <hip/hip_runtime.h>
#include <stdint.h>

// AugmentationPipeline: bit-exact JAX threefry (partitionable path) on device.
// Round 7: LDS row staging in STRIDED layout; crop = conflict-free rotated
// LDS gather (kills SEL8 cndmask trees + shuffles); reorder window via 5
// uniform-address broadcast LDS reads. All three outputs strided dword
// stores. s_bin aliases s_row (row dead once pass B starts). One wave per
// row, zero s_barriers.
// Out layout (int32): mask_seq[B*L] | mask_len[B] | crop_seq[B*L] | crop_len[B]
//                     | reord_seq[B*L] | reord_len[B]

#define NB 32768
#define NL 512
#define NBL (NB * NL)

struct AugKeys {
  uint32_t km0, km1;   // mask key
  uint32_t kc0, kc1;   // crop key
  uint32_t r10, r11;   // reorder k1 (wsize)
  uint32_t r20, r21;   // reorder k2 (start)
  uint32_t r30, r31;   // reorder k3 (apply)
  uint32_t r40, r41;   // reorder k4 (window keys, shape (B,5))
};

__host__ __device__ __forceinline__ uint32_t rotl32(uint32_t x, uint32_t r) {
  return (x << r) | (x >> (32u - r));
}

// Threefry-2x32, 20 rounds (JAX's threefry2x32_p).
__host__ __device__ inline void tf2x32(uint32_t k0, uint32_t k1,
                                       uint32_t x0, uint32_t x1,
                                       uint32_t& o0, uint32_t& o1) {
  const uint32_t ks2 = k0 ^ k1 ^ 0x1BD11BDAu;
#define TFR(r) { x0 += x1; x1 = rotl32(x1, r); x1 ^= x0; }
  x0 += k0; x1 += k1;
  TFR(13u) TFR(15u) TFR(26u) TFR(6u)
  x0 += k1; x1 += ks2 + 1u;
  TFR(17u) TFR(29u) TFR(16u) TFR(24u)
  x0 += ks2; x1 += k0 + 2u;
  TFR(13u) TFR(15u) TFR(26u) TFR(6u)
  x0 += k0; x1 += k1 + 3u;
  TFR(17u) TFR(29u) TFR(16u) TFR(24u)
  x0 += k1; x1 += ks2 + 4u;
  TFR(13u) TFR(15u) TFR(26u) TFR(6u)
  x0 += ks2; x1 += k0 + 5u;
#undef TFR
  o0 = x0; o1 = x1;
}

// JAX uniform(0,1) from 32 random bits.
__device__ __forceinline__ float u01f(uint32_t bits) {
  return __uint_as_float((bits >> 9) | 0x3F800000u) - 1.0f;
}

// 32-bit random bits for flat element index i (partitionable threefry):
// xor-fold of the two output words of block (hi=0, lo=i).
__device__ __forceinline__ uint32_t rbits32(uint32_t k0, uint32_t k1, uint32_t i) {
  uint32_t o0, o1;
  tf2x32(k0, k1, 0u, i, o0, o1);
  return o0 ^ o1;
}

__global__ void __launch_bounds__(256)
aug_pipeline(const int* __restrict__ seq, const int* __restrict__ lens,
             int* __restrict__ out, AugKeys K)
{
  __shared__ int s_row[4][NL];       // staged row; aliased as bin buffer later
  __shared__ int s_hist[4][128];
  __shared__ int s_nbin[4];

  const int t = threadIdx.x;
  const int w = t >> 6;        // row-in-block (wave id)
  const int l = t & 63;        // lane
  const int b = blockIdx.x * 4 + w;
  const int len = __builtin_amdgcn_readfirstlane(lens[b]);   // wave-uniform scalar
  const int* rowp = seq + (size_t)b * NL;

  // strided loads: es[it] = seq[b*512 + it*64 + l]  (8 x 256B coalesced)
  int es[8];
#pragma unroll
  for (int it = 0; it < 8; ++it) es[it] = rowp[(it << 6) + l];

  // stage row into wave-private LDS, strided (stride-1 across lanes: no conflicts)
#pragma unroll
  for (int it = 0; it < 8; ++it) s_row[w][(it << 6) + l] = es[it];

  // init wave-private hist early (in-order LDS, overlaps with compute below)
  s_hist[w][2 * l] = 0;
  s_hist[w][2 * l + 1] = 0;
  if (l == 0) s_nbin[w] = 0;

  // per-row uniforms (lanes 0..8), broadcast via shfl
  float uval = 0.f;
  if (l < 9) {
    uint32_t kk0, kk1, f;
    if (l == 0)      { kk0 = K.kc0; kk1 = K.kc1; f = (uint32_t)b; }
    else if (l == 1) { kk0 = K.r10; kk1 = K.r11; f = (uint32_t)b; }
    else if (l == 2) { kk0 = K.r20; kk1 = K.r21; f = (uint32_t)b; }
    else if (l == 3) { kk0 = K.r30; kk1 = K.r31; f = (uint32_t)b; }
    else             { kk0 = K.r40; kk1 = K.r41; f = (uint32_t)b * 5u + (uint32_t)(l - 4); }
    uval = u01f(rbits32(kk0, kk1, f));
  }
  const float u_c = __shfl(uval, 0);
  const float u_w = __shfl(uval, 1);
  const float u_s = __shfl(uval, 2);
  const float u_a = __shfl(uval, 3);
  float u4[5];
#pragma unroll
  for (int k = 0; k < 5; ++k) u4[k] = __shfl(uval, 4 + k);

  // strided validity + n_valid (ballot/popcount, scalar pipe)
  uint32_t vsm = 0;
  int nv = 0;
#pragma unroll
  for (int it = 0; it < 8; ++it) {
    const bool vs = ((it << 6) + l < len) && (es[it] != 0);
    vsm |= (uint32_t)vs << it;
    nv += (int)__popcll(__ballot(vs));
  }
  const int n_valid = __builtin_amdgcn_readfirstlane(nv);

  __builtin_amdgcn_wave_barrier();   // s_row staged (same-wave LDS is in-order)

  // ---- crop: rotated conflict-free LDS gather, strided store ----
  const int clen = min(max(3, (int)((float)len * 0.8f)), len);
  const int cms = max(len - clen + 1, 1);
  const int cstart = (int)(u_c * (float)cms);
  const bool apply_c = (len > 3);
  {
    int* cout = out + (size_t)NBL + NB + (size_t)b * NL;
#pragma unroll
    for (int it = 0; it < 8; ++it) {
      const int pos = (it << 6) + l;
      const int g = s_row[w][min(cstart + pos, NL - 1)];  // lane-stride 1: no conflict
      const int c = apply_c ? ((pos < clen) ? g : 0) : es[it];
      cout[pos] = c;
    }
  }

  // ---- lens outputs (early) ----
  if (l == 0) {
    out[(size_t)NBL + b] = len;                             // mask_len
    out[2 * (size_t)NBL + NB + b] = apply_c ? clen : len;   // crop_len
    out[3 * (size_t)NBL + 2 * NB + b] = len;                // reord_len
  }

  // ---- reorder: 5 uniform-address broadcast LDS reads, patch strided copy ----
  {
    const int max_w = min(n_valid, 5);
    int wsize = 2 + (int)(u_w * (float)max(max_w - 1, 1));
    wsize = min(max(wsize, 2), 5);
    const int rms = max(n_valid - wsize + 1, 1);
    const int rstart = (int)(u_s * (float)rms);
    const bool apply_r = (len > 2) && (u_a <= 0.3f) && (n_valid >= 2);

    int cols[5], items[5];
    float fk[5];
#pragma unroll
    for (int k = 0; k < 5; ++k) {
      cols[k] = min(rstart + k, NL - 1);          // valid_idx is identity
      items[k] = s_row[w][cols[k]];               // uniform addr: broadcast read
      fk[k] = (k < wsize) ? u4[k] : __int_as_float(0x7F800000);
    }
    // stable argsort of 5 via ranks (static indexing only)
    int rank5[5];
#pragma unroll
    for (int k = 0; k < 5; ++k) {
      int rr = 0;
#pragma unroll
      for (int j = 0; j < 5; ++j) {
        rr += ((fk[j] < fk[k]) || (fk[j] == fk[k] && j < k)) ? 1 : 0;
      }
      rank5[k] = rr;
    }
    int valk[5];
#pragma unroll
    for (int p = 0; p < 5; ++p) {
      int sh = items[0];
#pragma unroll
      for (int k = 0; k < 5; ++k) if (rank5[k] == p) sh = items[k];
      valk[p] = (apply_r && p < wsize) ? sh : items[p];
    }

    int r8[8] = {es[0], es[1], es[2], es[3], es[4], es[5], es[6], es[7]};
#pragma unroll
    for (int k = 0; k < 5; ++k) {  // ascending k: last dup write wins (XLA scatter order)
      const int ck = cols[k];
#pragma unroll
      for (int it = 0; it < 8; ++it) {
        if ((ck >> 6) == it && (ck & 63) == l) r8[it] = valk[k];
      }
    }
    int* rout = out + 2 * (size_t)NBL + 2 * NB + (size_t)b * NL;
#pragma unroll
    for (int it = 0; it < 8; ++it) rout[(it << 6) + l] = r8[it];
  }

  // ---- pass A: strided threefry + histogram; chunks past len skipped (scalar) ----
  // key = (bits & ~0x1FF) | pos : monotone == (score, idx), unique.
  uint32_t kk[8] = {0u, 0u, 0u, 0u, 0u, 0u, 0u, 0u};
#pragma unroll
  for (int it = 0; it < 8; ++it) {
    if ((it << 6) < len) {                     // wave-uniform (scalar) skip
      const int pos = (it << 6) + l;
      const uint32_t bits = rbits32(K.km0, K.km1, (uint32_t)b * NL + (uint32_t)pos);
      kk[it] = (bits & 0xFFFFFE00u) | (uint32_t)pos;
      if ((vsm >> it) & 1) atomicAdd(&s_hist[w][kk[it] >> 25], 1);
    }
  }
  __builtin_amdgcn_wave_barrier();

  // ---- 128-bin scan, 2 bins/lane, pure shuffle ----
  const int h0 = s_hist[w][2 * l];
  const int h1 = s_hist[w][2 * l + 1];
  const int pair = h0 + h1;
  int incl = pair;
#pragma unroll
  for (int d = 1; d < 64; d <<= 1) {
    const int o = __shfl_up(incl, d);
    if (l >= d) incl += o;
  }
  const int ex0 = incl - pair;
  const int ex1 = ex0 + h0;
  const int n_mask = min(max(1, (int)((float)n_valid * 0.2f)), n_valid);
  const bool c0 = (h0 > 0) && (ex0 < n_mask) && (n_mask <= ex0 + h0);
  const bool c1 = (h1 > 0) && (ex1 < n_mask) && (n_mask <= ex1 + h1);
  const unsigned long long B0 = __ballot(c0);
  const unsigned long long B1 = __ballot(c1);
  int tbin = -1, below = 0;
  if (B0) {
    const int tl = __ffsll(B0) - 1;
    tbin = 2 * tl; below = __shfl(ex0, tl);
  } else if (B1) {
    const int tl = __ffsll(B1) - 1;
    tbin = 2 * tl + 1; below = __shfl(ex1, tl);
  }
  const int need = n_mask - below;

  // ---- pass B: compact in-bin keys into s_row (row is dead now) ----
  uint32_t* s_bin = reinterpret_cast<uint32_t*>(s_row[w]);
#pragma unroll
  for (int it = 0; it < 8; ++it) {
    if (((vsm >> it) & 1) && (int)(kk[it] >> 25) == tbin) {
      s_bin[atomicAdd(&s_nbin[w], 1)] = kk[it];
    }
  }
  __builtin_amdgcn_wave_barrier();
  const int mtot = s_nbin[w];

  // ---- single rank pass over the threshold bin (broadcast LDS reads) ----
  int rk[8] = {0, 0, 0, 0, 0, 0, 0, 0};
  for (int j = 0; j < mtot; ++j) {
    const uint32_t bk = s_bin[j];
#pragma unroll
    for (int it = 0; it < 8; ++it) rk[it] += (bk < kk[it]) ? 1 : 0;
  }

  // ---- mask output: strided dword stores (256B coalesced per instruction) ----
  const bool apply_m = (len > 1) && (n_valid > 0);
  int* mout = out + (size_t)b * NL;
#pragma unroll
  for (int it = 0; it < 8; ++it) {
    const int bin = (int)(kk[it] >> 25);
    const bool dm = apply_m && ((vsm >> it) & 1) &&
                    (bin < tbin || (bin == tbin && rk[it] < need));
    mout[(it << 6) + l] = dm ? 0 : es[it];   // MASK_TOKEN = 0
  }
}

extern "C" void kernel_launch(void* const* d_in, const int* in_sizes, int n_in,
                              void* d_out, int out_size, void* d_ws, size_t ws_size,
                              hipStream_t stream) {
  const int* seq  = (const int*)d_in[0];
  const int* lens = (const int*)d_in[1];
  int* out = (int*)d_out;

  // key(42) = (0, 42). Partitionable (fold-like) split:
  // child i = full threefry block (counts hi=0, lo=i), key = (o0, o1).
  AugKeys K;
  uint32_t kr0, kr1;
  tf2x32(0u, 42u, 0u, 0u, K.km0, K.km1);  // km
  tf2x32(0u, 42u, 0u, 1u, K.kc0, K.kc1);  // kc
  tf2x32(0u, 42u, 0u, 2u, kr0, kr1);      // kr
  tf2x32(kr0, kr1, 0u, 0u, K.r10, K.r11); // k1
  tf2x32(kr0, kr1, 0u, 1u, K.r20, K.r21); // k2
  tf2x32(kr0, kr1, 0u, 2u, K.r30, K.r31); // k3
  tf2x32(kr0, kr1, 0u, 3u, K.r40, K.r41); // k4

  aug_pipeline<<<dim3(NB / 4), dim3(256), 0, stream>>>(seq, lens, out, K);
}